// Round 2
// baseline (66.552 us; speedup 1.0000x reference)
//
#include <hip/hip_runtime.h>
#include <hip/hip_bf16.h>

// WENO Black-Scholes time-stepper.
// M=80 (81 grid points), N_STEPS=26 (DT=1/26), strictly sequential steps.
// Single persistent block of 128 threads (2 waves); state lives in LDS,
// 3 __syncthreads per step. All fp32 (reference dtypes are float32).

#define MM 80
#define NSTEPS 26

__global__ __launch_bounds__(128)
void weno_bs_kernel(const float* __restrict__ om5,   // (80,3) fp32
                    const float* __restrict__ om6,   // (79,3) fp32
                    float* __restrict__ out)         // (81,)  fp32
{
    const float H      = 7.5f / 80.0f;          // 0.09375 (exact)
    const float DT     = 1.0f / 26.0f;
    const float SIG2H2 = 0.045f / (H * H);      // 0.5*sigma^2 / H^2
    const float ADV    = 0.055f;                // rate - 0.5*sigma^2
    const float RATE   = 0.1f;
    const float STRIKE = 50.0f;

    __shared__ float up[MM + 5];   // ghost(2) + u(81) + ghost(2) = 85
    __shared__ float uhat[MM];     // 80 fluxes

    const int i = threadIdx.x;

    // Per-thread WENO weights, loaded once.
    float w50 = 0.f, w51 = 0.f, w52 = 0.f;
    float w60 = 0.f, w61 = 0.f, w62 = 0.f;
    if (i < MM) {
        w50 = om5[3 * i + 0];
        w51 = om5[3 * i + 1];
        w52 = om5[3 * i + 2];
    }
    if (i >= 1 && i <= MM - 1) {
        const int j = i - 1;
        w60 = om6[3 * j + 0];
        w61 = om6[3 * j + 1];
        w62 = om6[3 * j + 2];
    }

    // u0 = max(K*exp(x) - K, 0), x_i = -6 + i*H
    if (i <= MM) {
        float x = -6.0f + (float)i * H;
        float S = STRIKE * expf(x);
        up[2 + i] = fmaxf(S - STRIKE, 0.0f);
    }
    const float s_right = STRIKE * expf(1.5f);
    float t = 0.0f;
    __syncthreads();

    for (int step = 0; step < NSTEPS; ++step) {
        // ---- ghosts (thread 0) ----
        if (i == 0) {
            float u0v = up[2];
            up[0] = u0v;
            up[1] = u0v;
            float d = up[2 + MM] - up[1 + MM];
            up[3 + MM] = up[2 + MM] + d;
            up[4 + MM] = up[2 + MM] + 2.0f * d;
        }
        __syncthreads();

        // ---- stencil window up[i..i+4]: WENO flux + 2nd-derivative ----
        float a0 = 0.f, a1 = 0.f, a2 = 0.f, a3 = 0.f, a4 = 0.f;
        float uxx = 0.f, uold = 0.f;
        if (i < MM) {
            a0 = up[i];     a1 = up[i + 1]; a2 = up[i + 2];
            a3 = up[i + 3]; a4 = up[i + 4];
            float f0 = (2.0f * a0 - 7.0f * a1 + 11.0f * a2) * (1.0f / 6.0f);
            float f1 = (-a1 + 5.0f * a2 + 2.0f * a3) * (1.0f / 6.0f);
            float f2 = (2.0f * a2 + 5.0f * a3 - a4) * (1.0f / 6.0f);
            uhat[i] = w50 * f0 + w51 * f1 + w52 * f2;
        }
        if (i >= 1 && i <= MM - 1) {
            // same window: uxx_i uses up[i..i+4]; note a2 == up[2+i] == u_i
            float c0 = a0 - 2.0f * a1 + a2;
            float c1 = a1 - 2.0f * a2 + a3;
            float c2 = a2 - 2.0f * a3 + a4;
            uxx  = w60 * c0 + w61 * c1 + w62 * c2;
            uold = a2;
        }
        t += DT;
        __syncthreads();

        // ---- Euler update + BCs (BC uses tn = t_old + DT == t here) ----
        if (i >= 1 && i <= MM - 1) {
            float ux = (uhat[i] - uhat[i - 1]) / H;
            float du = SIG2H2 * uxx + ADV * ux - RATE * uold;
            up[2 + i] = uold + DT * du;
        } else if (i == 0) {
            up[2] = 0.0f;
        } else if (i == MM) {
            up[2 + MM] = s_right - STRIKE * expf(-RATE * t);
        }
        __syncthreads();
    }

    if (i <= MM) {
        out[i] = up[2 + i];
    }
}

extern "C" void kernel_launch(void* const* d_in, const int* in_sizes, int n_in,
                              void* d_out, int out_size, void* d_ws, size_t ws_size,
                              hipStream_t stream) {
    const float* om5 = (const float*)d_in[0];
    const float* om6 = (const float*)d_in[1];
    float* out = (float*)d_out;
    weno_bs_kernel<<<dim3(1), dim3(128), 0, stream>>>(om5, om6, out);
}

// Round 4
// 60.954 us; speedup vs baseline: 1.0918x; 1.0918x over previous
//
#include <hip/hip_runtime.h>

// WENO Black-Scholes time-stepper — register/shuffle version.
// 81 grid points, 26 sequential Euler steps. One wave (64 lanes), 2 points
// per lane in registers (lane l holds u[2l], u[2l+1]). All neighbor access
// via __shfl_up/down(.,1): zero LDS, zero barriers. Per-step BC exp folded
// into a running multiply.
// (Resubmitted unchanged: Round 3 bench failed with GPUAcquisitionTimeout.)

#define MM 80
#define NSTEPS 26

__global__ __launch_bounds__(64)
void weno_bs_kernel(const float* __restrict__ om5,   // (80,3) fp32
                    const float* __restrict__ om6,   // (79,3) fp32
                    float* __restrict__ out)         // (81,)  fp32
{
    const float H      = 0.09375f;                    // (1.5-(-6))/80, exact
    const float INV_H  = 1.0f / 0.09375f;
    const float DT     = 1.0f / 26.0f;
    const float SIG2H2 = 0.045f / (0.09375f * 0.09375f);   // 0.5*sigma^2/H^2
    const float ADV    = 0.055f;                      // rate - 0.5*sigma^2
    const float RATE   = 0.1f;
    const float STRIKE = 50.0f;
    const float SIXTH  = 1.0f / 6.0f;

    const int l  = threadIdx.x;     // 0..63; lanes 0..40 carry real points
    const int p0 = 2 * l;           // even point index
    const int p1 = 2 * l + 1;       // odd point index

    // ---- per-lane weights (loaded once) ----
    // WENO5 flux weights: row i for uhat[i]  (i = p0, p1; valid i<80)
    float w5a0=0.f, w5a1=0.f, w5a2=0.f, w5b0=0.f, w5b1=0.f, w5b2=0.f;
    if (p0 < MM) { w5a0 = om5[3*p0+0]; w5a1 = om5[3*p0+1]; w5a2 = om5[3*p0+2]; }
    if (p1 < MM) { w5b0 = om5[3*p1+0]; w5b1 = om5[3*p1+1]; w5b2 = om5[3*p1+2]; }
    // 2nd-derivative weights: interior point p uses om6 row p-1 (rows 0..78)
    float w6a0=0.f, w6a1=0.f, w6a2=0.f, w6b0=0.f, w6b1=0.f, w6b2=0.f;
    if (p0 >= 1 && p0 <= MM-1) { int r = 3*(p0-1); w6a0=om6[r]; w6a1=om6[r+1]; w6a2=om6[r+2]; }
    if (p1 >= 1 && p1 <= MM-1) { int r = 3*(p1-1); w6b0=om6[r]; w6b1=om6[r+1]; w6b2=om6[r+2]; }

    // ---- initial condition: u = max(K*exp(x)-K, 0), x_p = -6 + p*H ----
    float u0 = 0.f, u1 = 0.f;
    if (p0 <= MM) u0 = fmaxf(STRIKE * expf(-6.0f + (float)p0 * H) - STRIKE, 0.0f);
    if (p1 <  MM) u1 = fmaxf(STRIKE * expf(-6.0f + (float)p1 * H) - STRIKE, 0.0f);

    const float s_right = STRIKE * expf(1.5f);
    const float F = expf(-RATE * DT);    // per-step discount factor
    float e = STRIKE;                    // e_n = K*exp(-r*t_n) via e *= F

    for (int s = 0; s < NSTEPS; ++s) {
        // neighbor windows: pm0=u[2l-2] pm1=u[2l-1] pp0=u[2l+2] pp1=u[2l+3]
        float pm0 = __shfl_up(u0, 1);
        float pm1 = __shfl_up(u1, 1);
        float pp0 = __shfl_down(u0, 1);
        float pp1 = __shfl_down(u1, 1);
        // ghosts: left u[-1]=u[-2]=u[0]; right u[81]=2*u[80]-u[79]
        if (l == 0)  { pm0 = u0; pm1 = u0; }
        if (l == 39) { pp1 = 2.0f * pp0 - u1; }   // pp0=u[80], u1=u[79]

        // WENO flux uhat[p0], uhat[p1]   (window u[i-2..i+2])
        float f0a = (2.0f*pm0 - 7.0f*pm1 + 11.0f*u0) * SIXTH;
        float f1a = (-pm1 + 5.0f*u0 + 2.0f*u1) * SIXTH;
        float f2a = (2.0f*u0 + 5.0f*u1 - pp0) * SIXTH;
        float uh0 = w5a0*f0a + w5a1*f1a + w5a2*f2a;

        float f0b = (2.0f*pm1 - 7.0f*u0 + 11.0f*u1) * SIXTH;
        float f1b = (-u0 + 5.0f*u1 + 2.0f*pp0) * SIXTH;
        float f2b = (2.0f*u1 + 5.0f*pp0 - pp1) * SIXTH;
        float uh1 = w5b0*f0b + w5b1*f1b + w5b2*f2b;

        // central 2nd-derivative combos (shared sub-expressions)
        float c0a = pm0 - 2.0f*pm1 + u0;
        float c1a = pm1 - 2.0f*u0  + u1;   // == c0 for point p1
        float c2a = u0  - 2.0f*u1  + pp0;  // == c1 for point p1
        float c2b = u1  - 2.0f*pp0 + pp1;
        float uxx0 = w6a0*c0a + w6a1*c1a + w6a2*c2a;
        float uxx1 = w6b0*c1a + w6b1*c2a + w6b2*c2b;

        // uhat[p0-1] lives in lane l-1's uh1
        float uhm = __shfl_up(uh1, 1);

        float nu0 = u0 + DT*(SIG2H2*uxx0 + ADV*((uh0 - uhm)*INV_H) - RATE*u0);
        float nu1 = u1 + DT*(SIG2H2*uxx1 + ADV*((uh1 - uh0)*INV_H) - RATE*u1);

        e *= F;
        // interior updates: even points 2..78 (lanes 1..39), odd 1..79 (0..39)
        if (l >= 1 && l <= 39) u0 = nu0;
        if (l <= 39)           u1 = nu1;
        if (l == 40)           u0 = s_right - e;   // right BC at t_{n+1}
        // lane 0: u0 stays 0 (left BC)
    }

    if (p0 <= MM) out[p0] = u0;
    if (p1 <= MM) out[p1] = u1;
}

extern "C" void kernel_launch(void* const* d_in, const int* in_sizes, int n_in,
                              void* d_out, int out_size, void* d_ws, size_t ws_size,
                              hipStream_t stream) {
    const float* om5 = (const float*)d_in[0];
    const float* om6 = (const float*)d_in[1];
    float* out = (float*)d_out;
    weno_bs_kernel<<<dim3(1), dim3(64), 0, stream>>>(om5, om6, out);
}